// Round 1
// baseline (305.447 us; speedup 1.0000x reference)
//
#include <hip/hip_runtime.h>
#include <hip/hip_bf16.h>
#include <math.h>

#define SEQ 512
#define DM 512
#define NH 8
#define DKH 64
#define EPSV 1e-6f
#define LN2F 0.6931471805599453f

// ---------------------------------------------------------------------------
// Kernel P: six fused projections  C[s,o] = sum_k X[s,k] * W[o,k] + b[o]
// 64x64 tiles, 256 threads, 4x4 microtile, K-step 16, LDS stored transposed
// [k][m] with row stride 68 floats (16B-aligned, conflict-free float4 reads).
// ---------------------------------------------------------------------------
struct ProjArgs {
  const float* x[6];
  const float* w[6];
  const float* b[6];
  float*       o[6];
};

__global__ __launch_bounds__(256) void proj_kernel(ProjArgs args) {
  const int p  = blockIdx.z;
  const int bm = blockIdx.y * 64;
  const int bn = blockIdx.x * 64;
  const float* __restrict__ X  = args.x[p];
  const float* __restrict__ W  = args.w[p];
  const float* __restrict__ Bv = args.b[p];
  float* __restrict__       C  = args.o[p];

  __shared__ float As[16][68];
  __shared__ float Bs[16][68];

  const int t  = threadIdx.x;
  const int tx = t & 15, ty = t >> 4;
  const int lr = t >> 2, lq = t & 3;   // load: row 0..63, k-quad 0..3

  float acc[4][4] = {};

  for (int k0 = 0; k0 < DM; k0 += 16) {
    float4 av = *(const float4*)&X[(bm + lr) * DM + k0 + lq * 4];
    float4 bv = *(const float4*)&W[(bn + lr) * DM + k0 + lq * 4];
    __syncthreads();
    As[lq * 4 + 0][lr] = av.x; As[lq * 4 + 1][lr] = av.y;
    As[lq * 4 + 2][lr] = av.z; As[lq * 4 + 3][lr] = av.w;
    Bs[lq * 4 + 0][lr] = bv.x; Bs[lq * 4 + 1][lr] = bv.y;
    Bs[lq * 4 + 2][lr] = bv.z; Bs[lq * 4 + 3][lr] = bv.w;
    __syncthreads();
#pragma unroll
    for (int kk = 0; kk < 16; ++kk) {
      float4 a4 = *(const float4*)&As[kk][ty * 4];
      float4 b4 = *(const float4*)&Bs[kk][tx * 4];
      float a[4] = {a4.x, a4.y, a4.z, a4.w};
      float b[4] = {b4.x, b4.y, b4.z, b4.w};
#pragma unroll
      for (int i = 0; i < 4; ++i)
#pragma unroll
        for (int j = 0; j < 4; ++j)
          acc[i][j] = fmaf(a[i], b[j], acc[i][j]);
    }
  }

#pragma unroll
  for (int j = 0; j < 4; ++j) {
    float bias = Bv[bn + tx * 4 + j];
#pragma unroll
    for (int i = 0; i < 4; ++i)
      C[(bm + ty * 4 + i) * DM + bn + tx * 4 + j] = acc[i][j] + bias;
  }
}

// ---------------------------------------------------------------------------
// Kernel Q: in-place a = sg^2 (+eps), plus per-(s,h) log-sums La/Lc.
// One wave per (s,h): lane = d.  role 0 -> sq->aq + La, 1 -> sk->ak + Lc,
// 2 -> sv -> sv^2 (no eps, no log).
// ---------------------------------------------------------------------------
__global__ __launch_bounds__(256) void prep_kernel(float* sq, float* sk, float* sv,
                                                   float* La, float* Lc) {
  const int role = blockIdx.y;
  const int gid  = blockIdx.x * 256 + threadIdx.x;
  const int wid  = gid >> 6;     // (s,h) index: s*8+h, 0..4095
  const int lane = gid & 63;     // d
  float* buf = (role == 0) ? sq : (role == 1) ? sk : sv;
  const int idx = wid * 64 + lane;
  float v = buf[idx];
  float a = fmaf(v, v, (role == 2) ? 0.f : EPSV);
  buf[idx] = a;
  if (role < 2) {
    float l = __logf(a);   // natural log
#pragma unroll
    for (int o = 32; o; o >>= 1) l += __shfl_xor(l, o, 64);
    if (lane == 0) ((role == 0) ? La : Lc)[wid] = l;
  }
}

// ---------------------------------------------------------------------------
// Kernel D: distance matrix, lower-triangle 32x32 tiles only.
// dist(q,k,h) = [0.5*ln2*sum_d log2(a+c) + 0.25*sum_d dmu^2/(a+c-eps)
//                - 0.25*(La+Lc) - 32*ln2] / 8
// Thread t: qi = t>>3, k = (t&7) + 8j, j=0..3 (bank-conflict-free strided k).
// ---------------------------------------------------------------------------
__global__ __launch_bounds__(256) void dist_kernel(const float* __restrict__ aq,
                                                   const float* __restrict__ ak,
                                                   const float* __restrict__ mq,
                                                   const float* __restrict__ mk,
                                                   const float* __restrict__ La,
                                                   const float* __restrict__ Lc,
                                                   float* __restrict__ dist) {
  const int blk = blockIdx.x;
  const int h = blk / 136;
  const int tt = blk % 136;
  int qt = (int)((sqrtf(8.f * tt + 1.f) - 1.f) * 0.5f);
  while ((qt + 1) * (qt + 2) / 2 <= tt) ++qt;
  while (qt * (qt + 1) / 2 > tt) --qt;
  const int kt = tt - qt * (qt + 1) / 2;

  __shared__ float aqs[32][68], mqs[32][68], aks[32][68], mks[32][68];
  const int t = threadIdx.x;
#pragma unroll
  for (int i = 0; i < 2; ++i) {
    int idx = t + 256 * i;
    int r = idx >> 4, c4 = idx & 15;
    int gq = (qt * 32 + r) * DM + h * 64 + c4 * 4;
    int gk = (kt * 32 + r) * DM + h * 64 + c4 * 4;
    *(float4*)&aqs[r][c4 * 4] = *(const float4*)&aq[gq];
    *(float4*)&mqs[r][c4 * 4] = *(const float4*)&mq[gq];
    *(float4*)&aks[r][c4 * 4] = *(const float4*)&ak[gk];
    *(float4*)&mks[r][c4 * 4] = *(const float4*)&mk[gk];
  }
  __syncthreads();

  const int qi = t >> 3;
  const int kb = t & 7;
  float accl[4] = {0.f, 0.f, 0.f, 0.f};
  float acct[4] = {0.f, 0.f, 0.f, 0.f};

  for (int d4 = 0; d4 < 16; ++d4) {
    float4 qa = *(const float4*)&aqs[qi][d4 * 4];
    float4 qm = *(const float4*)&mqs[qi][d4 * 4];
    float qaa[4] = {qa.x, qa.y, qa.z, qa.w};
    float qmm[4] = {qm.x, qm.y, qm.z, qm.w};
#pragma unroll
    for (int j = 0; j < 4; ++j) {
      int ki = kb + 8 * j;
      float4 ca = *(const float4*)&aks[ki][d4 * 4];
      float4 cm = *(const float4*)&mks[ki][d4 * 4];
      float caa[4] = {ca.x, ca.y, ca.z, ca.w};
      float cmm[4] = {cm.x, cm.y, cm.z, cm.w};
#pragma unroll
      for (int e = 0; e < 4; ++e) {
        float s = qaa[e] + caa[e];
        accl[j] += __log2f(s);
        float dm = qmm[e] - cmm[e];
        float r = __builtin_amdgcn_rcpf(s - EPSV);
        acct[j] = fmaf(dm * dm, r, acct[j]);
      }
    }
  }

  const int qg = qt * 32 + qi;
  const float la = La[qg * 8 + h];
#pragma unroll
  for (int j = 0; j < 4; ++j) {
    int kg = kt * 32 + kb + 8 * j;
    float lc = Lc[kg * 8 + h];
    float dv = (0.5f * LN2F * accl[j] + 0.25f * acct[j]
                - 0.25f * (la + lc) - 32.f * LN2F) * 0.125f;
    dist[(h * SEQ + qg) * SEQ + kg] = dv;
  }
}

// ---------------------------------------------------------------------------
// Kernel S: causal softmax per (h,q) row; writes 0 for k>q so PV can do a
// full dense 512 reduction.
// ---------------------------------------------------------------------------
__global__ __launch_bounds__(256) void softmax_kernel(float* __restrict__ dist) {
  const int gid  = blockIdx.x * 256 + threadIdx.x;
  const int wid  = gid >> 6;        // h*512+q
  const int lane = gid & 63;
  const int q = wid & 511;
  float* row = dist + wid * SEQ;

  float vals[8];
  float m = -1e30f;
#pragma unroll
  for (int i = 0; i < 8; ++i) {
    int k = lane + 64 * i;
    float v = (k <= q) ? row[k] : -1e30f;
    vals[i] = v;
    m = fmaxf(m, v);
  }
#pragma unroll
  for (int o = 32; o; o >>= 1) m = fmaxf(m, __shfl_xor(m, o, 64));
  float ssum = 0.f;
#pragma unroll
  for (int i = 0; i < 8; ++i) {
    int k = lane + 64 * i;
    float p = (k <= q) ? __expf(vals[i] - m) : 0.f;
    vals[i] = p;
    ssum += p;
  }
#pragma unroll
  for (int o = 32; o; o >>= 1) ssum += __shfl_xor(ssum, o, 64);
  float rs = 1.f / ssum;
#pragma unroll
  for (int i = 0; i < 8; ++i) row[lane + 64 * i] = vals[i] * rs;
}

// ---------------------------------------------------------------------------
// Kernel V: out_mu = attn @ mu_v ; out_sigma = sqrt(max(attn @ sv2,0)+eps).
// Block = (h, 16-row q-tile); 256 threads; thread owns (d, 4 q-rows).
// ---------------------------------------------------------------------------
__global__ __launch_bounds__(256) void pv_kernel(const float* __restrict__ attn,
                                                 const float* __restrict__ mv,
                                                 const float* __restrict__ sv2,
                                                 float* __restrict__ out) {
  const int h  = blockIdx.x >> 5;
  const int qt = blockIdx.x & 31;   // 16 rows per tile

  __shared__ float ats[16][68];
  __shared__ float mvs[64][68];
  __shared__ float svs[64][68];

  const int t  = threadIdx.x;
  const int d  = t & 63;
  const int q0 = t >> 6;            // wave id 0..3

  float amu[4] = {0.f, 0.f, 0.f, 0.f};
  float avr[4] = {0.f, 0.f, 0.f, 0.f};

  for (int kt = 0; kt < 8; ++kt) {
    __syncthreads();
    {
      int r = t >> 4, c4 = t & 15;
      *(float4*)&ats[r][c4 * 4] =
          *(const float4*)&attn[(h * SEQ + qt * 16 + r) * SEQ + kt * 64 + c4 * 4];
    }
#pragma unroll
    for (int i = 0; i < 4; ++i) {
      int idx = t + 256 * i;
      int r = idx >> 4, c4 = idx & 15;
      int g = (kt * 64 + r) * DM + h * 64 + c4 * 4;
      *(float4*)&mvs[r][c4 * 4] = *(const float4*)&mv[g];
      *(float4*)&svs[r][c4 * 4] = *(const float4*)&sv2[g];
    }
    __syncthreads();
    for (int k = 0; k < 64; ++k) {
      float mvv = mvs[k][d];
      float svv = svs[k][d];
#pragma unroll
      for (int i = 0; i < 4; ++i) {
        float a = ats[q0 + 4 * i][k];
        amu[i] = fmaf(a, mvv, amu[i]);
        avr[i] = fmaf(a, svv, avr[i]);
      }
    }
  }

  float* out_mu = out;
  float* out_sg = out + NH * SEQ * DKH;
#pragma unroll
  for (int i = 0; i < 4; ++i) {
    int q = qt * 16 + q0 + 4 * i;
    int o = (h * SEQ + q) * DKH + d;
    out_mu[o] = amu[i];
    out_sg[o] = sqrtf(fmaxf(avr[i], 0.f) + EPSV);
  }
}

// ---------------------------------------------------------------------------
extern "C" void kernel_launch(void* const* d_in, const int* in_sizes, int n_in,
                              void* d_out, int out_size, void* d_ws, size_t ws_size,
                              hipStream_t stream) {
  (void)in_sizes; (void)n_in; (void)out_size; (void)ws_size;

  float* ws = (float*)d_ws;
  float* mq = ws;                 // 512*512
  float* mk = mq + 262144;
  float* mv = mk + 262144;
  float* sq = mv + 262144;        // becomes aq in-place
  float* sk = sq + 262144;        // becomes ak in-place
  float* sv = sk + 262144;        // becomes sv^2 in-place
  float* La = sv + 262144;        // 4096
  float* Lc = La + 4096;          // 4096
  float* dist = Lc + 4096;        // 8*512*512

  ProjArgs pa;
  pa.x[0] = (const float*)d_in[0]; pa.w[0] = (const float*)d_in[6];  pa.b[0] = (const float*)d_in[7];  pa.o[0] = mq;
  pa.x[1] = (const float*)d_in[1]; pa.w[1] = (const float*)d_in[8];  pa.b[1] = (const float*)d_in[9];  pa.o[1] = mk;
  pa.x[2] = (const float*)d_in[2]; pa.w[2] = (const float*)d_in[10]; pa.b[2] = (const float*)d_in[11]; pa.o[2] = mv;
  pa.x[3] = (const float*)d_in[3]; pa.w[3] = (const float*)d_in[12]; pa.b[3] = (const float*)d_in[13]; pa.o[3] = sq;
  pa.x[4] = (const float*)d_in[4]; pa.w[4] = (const float*)d_in[14]; pa.b[4] = (const float*)d_in[15]; pa.o[4] = sk;
  pa.x[5] = (const float*)d_in[5]; pa.w[5] = (const float*)d_in[16]; pa.b[5] = (const float*)d_in[17]; pa.o[5] = sv;

  dim3 pgrid(8, 8, 6);
  proj_kernel<<<pgrid, 256, 0, stream>>>(pa);

  dim3 qgrid(1024, 3);
  prep_kernel<<<qgrid, 256, 0, stream>>>(sq, sk, sv, La, Lc);

  dist_kernel<<<8 * 136, 256, 0, stream>>>(sq, sk, mq, mk, La, Lc, dist);

  softmax_kernel<<<1024, 256, 0, stream>>>(dist);

  pv_kernel<<<256, 256, 0, stream>>>(dist, mv, sv, (float*)d_out);
}

// Round 2
// 209.654 us; speedup vs baseline: 1.4569x; 1.4569x over previous
//
#include <hip/hip_runtime.h>
#include <hip/hip_bf16.h>
#include <math.h>

#define SEQ 512
#define DM 512
#define NH 8
#define DKH 64
#define EPSV 1e-6f
#define LN2F 0.6931471805599453f

// ---------------------------------------------------------------------------
// Kernel P: six fused projections  C[s,o] = sum_k X[s,k] * W[o,k] + b[o]
// 64x64 tiles, 256 threads, 4x4 microtile, K-step 16, LDS stored transposed
// [k][m] with row stride 68 floats (16B-aligned, conflict-free float4 reads).
// ---------------------------------------------------------------------------
struct ProjArgs {
  const float* x[6];
  const float* w[6];
  const float* b[6];
  float*       o[6];
};

__global__ __launch_bounds__(256) void proj_kernel(ProjArgs args) {
  const int p  = blockIdx.z;
  const int bm = blockIdx.y * 64;
  const int bn = blockIdx.x * 64;
  const float* __restrict__ X  = args.x[p];
  const float* __restrict__ W  = args.w[p];
  const float* __restrict__ Bv = args.b[p];
  float* __restrict__       C  = args.o[p];

  __shared__ float As[16][68];
  __shared__ float Bs[16][68];

  const int t  = threadIdx.x;
  const int tx = t & 15, ty = t >> 4;
  const int lr = t >> 2, lq = t & 3;   // load: row 0..63, k-quad 0..3

  float acc[4][4] = {};

  for (int k0 = 0; k0 < DM; k0 += 16) {
    float4 av = *(const float4*)&X[(bm + lr) * DM + k0 + lq * 4];
    float4 bv = *(const float4*)&W[(bn + lr) * DM + k0 + lq * 4];
    __syncthreads();
    As[lq * 4 + 0][lr] = av.x; As[lq * 4 + 1][lr] = av.y;
    As[lq * 4 + 2][lr] = av.z; As[lq * 4 + 3][lr] = av.w;
    Bs[lq * 4 + 0][lr] = bv.x; Bs[lq * 4 + 1][lr] = bv.y;
    Bs[lq * 4 + 2][lr] = bv.z; Bs[lq * 4 + 3][lr] = bv.w;
    __syncthreads();
#pragma unroll 8
    for (int kk = 0; kk < 16; ++kk) {
      float4 a4 = *(const float4*)&As[kk][ty * 4];
      float4 b4 = *(const float4*)&Bs[kk][tx * 4];
      float a[4] = {a4.x, a4.y, a4.z, a4.w};
      float b[4] = {b4.x, b4.y, b4.z, b4.w};
#pragma unroll
      for (int i = 0; i < 4; ++i)
#pragma unroll
        for (int j = 0; j < 4; ++j)
          acc[i][j] = fmaf(a[i], b[j], acc[i][j]);
    }
  }

#pragma unroll
  for (int j = 0; j < 4; ++j) {
    float bias = Bv[bn + tx * 4 + j];
#pragma unroll
    for (int i = 0; i < 4; ++i)
      C[(bm + ty * 4 + i) * DM + bn + tx * 4 + j] = acc[i][j] + bias;
  }
}

// ---------------------------------------------------------------------------
// Kernel Q: in-place a = sg^2 (+eps), plus per-(s,h) log-sums La/Lc.
// ---------------------------------------------------------------------------
__global__ __launch_bounds__(256) void prep_kernel(float* sq, float* sk, float* sv,
                                                   float* La, float* Lc) {
  const int role = blockIdx.y;
  const int gid  = blockIdx.x * 256 + threadIdx.x;
  const int wid  = gid >> 6;     // (s,h) index: s*8+h, 0..4095
  const int lane = gid & 63;     // d
  float* buf = (role == 0) ? sq : (role == 1) ? sk : sv;
  const int idx = wid * 64 + lane;
  float v = buf[idx];
  float a = fmaf(v, v, (role == 2) ? 0.f : EPSV);
  buf[idx] = a;
  if (role < 2) {
    float l = __logf(a);   // natural log
#pragma unroll
    for (int o = 32; o; o >>= 1) l += __shfl_xor(l, o, 64);
    if (lane == 0) ((role == 0) ? La : Lc)[wid] = l;
  }
}

// ---------------------------------------------------------------------------
// Kernel D: distance matrix, lower-triangle 32x32 tiles only.
// dist(q,k,h) = [0.5*ln2*sum_d log2(a+c) + 0.25*sum_d dmu^2/(a+c-eps)
//                - 0.25*(La+Lc) - 32*ln2] / 8
// #pragma unroll 2 on the d4 loop: full unroll (16x ~40 live floats) spills.
// ---------------------------------------------------------------------------
__global__ __launch_bounds__(256) void dist_kernel(const float* __restrict__ aq,
                                                   const float* __restrict__ ak,
                                                   const float* __restrict__ mq,
                                                   const float* __restrict__ mk,
                                                   const float* __restrict__ La,
                                                   const float* __restrict__ Lc,
                                                   float* __restrict__ dist) {
  const int blk = blockIdx.x;
  const int h = blk / 136;
  const int tt = blk % 136;
  int qt = (int)((sqrtf(8.f * tt + 1.f) - 1.f) * 0.5f);
  while ((qt + 1) * (qt + 2) / 2 <= tt) ++qt;
  while (qt * (qt + 1) / 2 > tt) --qt;
  const int kt = tt - qt * (qt + 1) / 2;

  __shared__ float aqs[32][68], mqs[32][68], aks[32][68], mks[32][68];
  const int t = threadIdx.x;
#pragma unroll
  for (int i = 0; i < 2; ++i) {
    int idx = t + 256 * i;
    int r = idx >> 4, c4 = idx & 15;
    int gq = (qt * 32 + r) * DM + h * 64 + c4 * 4;
    int gk = (kt * 32 + r) * DM + h * 64 + c4 * 4;
    *(float4*)&aqs[r][c4 * 4] = *(const float4*)&aq[gq];
    *(float4*)&mqs[r][c4 * 4] = *(const float4*)&mq[gq];
    *(float4*)&aks[r][c4 * 4] = *(const float4*)&ak[gk];
    *(float4*)&mks[r][c4 * 4] = *(const float4*)&mk[gk];
  }
  __syncthreads();

  const int qi = t >> 3;
  const int kb = t & 7;
  float accl[4] = {0.f, 0.f, 0.f, 0.f};
  float acct[4] = {0.f, 0.f, 0.f, 0.f};

#pragma unroll 2
  for (int d4 = 0; d4 < 16; ++d4) {
    float4 qa = *(const float4*)&aqs[qi][d4 * 4];
    float4 qm = *(const float4*)&mqs[qi][d4 * 4];
    float qaa[4] = {qa.x, qa.y, qa.z, qa.w};
    float qmm[4] = {qm.x, qm.y, qm.z, qm.w};
#pragma unroll
    for (int j = 0; j < 4; ++j) {
      int ki = kb + 8 * j;
      float4 ca = *(const float4*)&aks[ki][d4 * 4];
      float4 cm = *(const float4*)&mks[ki][d4 * 4];
      float caa[4] = {ca.x, ca.y, ca.z, ca.w};
      float cmm[4] = {cm.x, cm.y, cm.z, cm.w};
#pragma unroll
      for (int e = 0; e < 4; ++e) {
        float s = qaa[e] + caa[e];
        accl[j] += __log2f(s);
        float dm = qmm[e] - cmm[e];
        float r = __builtin_amdgcn_rcpf(s - EPSV);
        acct[j] = fmaf(dm * dm, r, acct[j]);
      }
    }
  }

  const int qg = qt * 32 + qi;
  const float la = La[qg * 8 + h];
#pragma unroll
  for (int j = 0; j < 4; ++j) {
    int kg = kt * 32 + kb + 8 * j;
    float lc = Lc[kg * 8 + h];
    float dv = (0.5f * LN2F * accl[j] + 0.25f * acct[j]
                - 0.25f * (la + lc) - 32.f * LN2F) * 0.125f;
    dist[(h * SEQ + qg) * SEQ + kg] = dv;
  }
}

// ---------------------------------------------------------------------------
// Kernel S: causal softmax per (h,q) row; writes 0 for k>q so PV can read
// dense within its causal k-range.
// ---------------------------------------------------------------------------
__global__ __launch_bounds__(256) void softmax_kernel(float* __restrict__ dist) {
  const int gid  = blockIdx.x * 256 + threadIdx.x;
  const int wid  = gid >> 6;        // h*512+q
  const int lane = gid & 63;
  const int q = wid & 511;
  float* row = dist + wid * SEQ;

  float vals[8];
  float m = -1e30f;
#pragma unroll
  for (int i = 0; i < 8; ++i) {
    int k = lane + 64 * i;
    float v = (k <= q) ? row[k] : -1e30f;
    vals[i] = v;
    m = fmaxf(m, v);
  }
#pragma unroll
  for (int o = 32; o; o >>= 1) m = fmaxf(m, __shfl_xor(m, o, 64));
  float ssum = 0.f;
#pragma unroll
  for (int i = 0; i < 8; ++i) {
    int k = lane + 64 * i;
    float p = (k <= q) ? __expf(vals[i] - m) : 0.f;
    vals[i] = p;
    ssum += p;
  }
#pragma unroll
  for (int o = 32; o; o >>= 1) ssum += __shfl_xor(ssum, o, 64);
  float rs = 1.f / ssum;
#pragma unroll
  for (int i = 0; i < 8; ++i) row[lane + 64 * i] = vals[i] * rs;
}

// ---------------------------------------------------------------------------
// Kernel V (rewritten): out_mu = attn @ mu_v ; out_sigma = sqrt(attn @ sv2 + eps).
// No LDS. Block = (h, 16-row q-tile); 4 waves; wave w owns rows q0..q0+3
// (wave-uniform via readfirstlane -> attn loads are scalar/broadcast), lane = d
// reads V coalesced (256B/wave, L1/L2-resident: V is 2 MB total).
// Causal: this tile only needs k < (qt+1)*16 -> ~2x less work on average.
// #pragma unroll 4 caps register pressure (the old version fully unrolled
// k=0..63 with 6 LDS reads/iter -> 256 VGPR + 176 MB of scratch spill).
// ---------------------------------------------------------------------------
__global__ __launch_bounds__(256) void pv_kernel(const float* __restrict__ attn,
                                                 const float* __restrict__ mv,
                                                 const float* __restrict__ sv2,
                                                 float* __restrict__ out) {
  const int h  = blockIdx.x >> 5;
  const int qt = blockIdx.x & 31;   // 16-row q-tile
  const int t  = threadIdx.x;
  const int d  = t & 63;
  const int w  = __builtin_amdgcn_readfirstlane(t >> 6);  // wave id, uniform

  const int q0 = qt * 16 + w * 4;
  const float* __restrict__ a0 = attn + (size_t)(h * SEQ + q0 + 0) * SEQ;
  const float* __restrict__ a1 = attn + (size_t)(h * SEQ + q0 + 1) * SEQ;
  const float* __restrict__ a2 = attn + (size_t)(h * SEQ + q0 + 2) * SEQ;
  const float* __restrict__ a3 = attn + (size_t)(h * SEQ + q0 + 3) * SEQ;
  const float* __restrict__ vp = mv  + h * 64 + d;
  const float* __restrict__ sp = sv2 + h * 64 + d;

  float m0 = 0.f, m1 = 0.f, m2 = 0.f, m3 = 0.f;
  float s0 = 0.f, s1 = 0.f, s2 = 0.f, s3 = 0.f;

  const int kmax = qt * 16 + 16;    // attn is 0 for k > q; rows here have q < kmax
#pragma unroll 4
  for (int k = 0; k < kmax; ++k) {
    float v = vp[(size_t)k * DM];
    float s = sp[(size_t)k * DM];
    float w0 = a0[k], w1 = a1[k], w2 = a2[k], w3 = a3[k];
    m0 = fmaf(w0, v, m0); s0 = fmaf(w0, s, s0);
    m1 = fmaf(w1, v, m1); s1 = fmaf(w1, s, s1);
    m2 = fmaf(w2, v, m2); s2 = fmaf(w2, s, s2);
    m3 = fmaf(w3, v, m3); s3 = fmaf(w3, s, s3);
  }

  float* out_mu = out;
  float* out_sg = out + NH * SEQ * DKH;
  float mu[4] = {m0, m1, m2, m3};
  float sg[4] = {s0, s1, s2, s3};
#pragma unroll
  for (int i = 0; i < 4; ++i) {
    int o = (h * SEQ + q0 + i) * DKH + d;
    out_mu[o] = mu[i];
    out_sg[o] = sqrtf(fmaxf(sg[i], 0.f) + EPSV);
  }
}

// ---------------------------------------------------------------------------
extern "C" void kernel_launch(void* const* d_in, const int* in_sizes, int n_in,
                              void* d_out, int out_size, void* d_ws, size_t ws_size,
                              hipStream_t stream) {
  (void)in_sizes; (void)n_in; (void)out_size; (void)ws_size;

  float* ws = (float*)d_ws;
  float* mq = ws;                 // 512*512
  float* mk = mq + 262144;
  float* mv = mk + 262144;
  float* sq = mv + 262144;        // becomes aq in-place
  float* sk = sq + 262144;        // becomes ak in-place
  float* sv = sk + 262144;        // becomes sv^2 in-place
  float* La = sv + 262144;        // 4096
  float* Lc = La + 4096;          // 4096
  float* dist = Lc + 4096;        // 8*512*512

  ProjArgs pa;
  pa.x[0] = (const float*)d_in[0]; pa.w[0] = (const float*)d_in[6];  pa.b[0] = (const float*)d_in[7];  pa.o[0] = mq;
  pa.x[1] = (const float*)d_in[1]; pa.w[1] = (const float*)d_in[8];  pa.b[1] = (const float*)d_in[9];  pa.o[1] = mk;
  pa.x[2] = (const float*)d_in[2]; pa.w[2] = (const float*)d_in[10]; pa.b[2] = (const float*)d_in[11]; pa.o[2] = mv;
  pa.x[3] = (const float*)d_in[3]; pa.w[3] = (const float*)d_in[12]; pa.b[3] = (const float*)d_in[13]; pa.o[3] = sq;
  pa.x[4] = (const float*)d_in[4]; pa.w[4] = (const float*)d_in[14]; pa.b[4] = (const float*)d_in[15]; pa.o[4] = sk;
  pa.x[5] = (const float*)d_in[5]; pa.w[5] = (const float*)d_in[16]; pa.b[5] = (const float*)d_in[17]; pa.o[5] = sv;

  dim3 pgrid(8, 8, 6);
  proj_kernel<<<pgrid, 256, 0, stream>>>(pa);

  dim3 qgrid(1024, 3);
  prep_kernel<<<qgrid, 256, 0, stream>>>(sq, sk, sv, La, Lc);

  dist_kernel<<<8 * 136, 256, 0, stream>>>(sq, sk, mq, mk, La, Lc, dist);

  softmax_kernel<<<1024, 256, 0, stream>>>(dist);

  pv_kernel<<<256, 256, 0, stream>>>(dist, mv, sv, (float*)d_out);
}

// Round 4
// 193.260 us; speedup vs baseline: 1.5805x; 1.0848x over previous
//
#include <hip/hip_runtime.h>
#include <hip/hip_bf16.h>
#include <math.h>

#define SEQ 512
#define DM 512
#define NH 8
#define DKH 64
#define EPSV 1e-6f
#define LN2F 0.6931471805599453f

typedef __attribute__((ext_vector_type(8))) short short8v;
typedef __attribute__((ext_vector_type(8))) unsigned short ushort8v;
typedef __attribute__((ext_vector_type(16))) float f32x16;

__device__ inline unsigned short f2bf(float x) {
  union { float f; unsigned u; } v; v.f = x;
  unsigned r = v.u + 0x7FFFu + ((v.u >> 16) & 1u);
  return (unsigned short)(r >> 16);
}
__device__ inline float bf2f(unsigned short h) {
  union { float f; unsigned u; } v; v.u = ((unsigned)h) << 16;
  return v.f;
}

// ---------------------------------------------------------------------------
// Kernel C: convert 12 fp32 512x512 matrices (6 X, 6 W) into a 3-level bf16
// split (x = h1 + h2 + h3, representation error ~2^-27 |x|) in fragment-ready
// layout: pack[m][level][panel p][k-octet ko][row r][8 bf16],
//   element = M[p*32 + r][ko*8 + e]
// so a GEMM wave's mfma_32x32x16 fragment load (lane l: row l&31, k-octet
// l>>5) is one fully-coalesced 1KB dwordx4 load. 16B stores, coalesced.
// ---------------------------------------------------------------------------
struct ConvArgs { const float* src[12]; };

__global__ __launch_bounds__(256) void convert_kernel(ConvArgs a,
                                                      unsigned short* __restrict__ pack) {
  const int m = blockIdx.x >> 7;                        // matrix 0..11
  const int g = ((blockIdx.x & 127) << 8) + threadIdx.x; // 0..32767
  const int r = g & 31, ko = (g >> 5) & 63, p = g >> 11;
  const float* src = a.src[m] + (p * 32 + r) * DM + ko * 8;
  float4 x0 = *(const float4*)src;
  float4 x1 = *(const float4*)(src + 4);
  float xs[8] = {x0.x, x0.y, x0.z, x0.w, x1.x, x1.y, x1.z, x1.w};
  ushort8v h1, h2, h3;
#pragma unroll
  for (int e = 0; e < 8; ++e) {
    unsigned short a1 = f2bf(xs[e]);
    float r1 = xs[e] - bf2f(a1);
    unsigned short a2 = f2bf(r1);
    float r2 = r1 - bf2f(a2);
    h1[e] = a1; h2[e] = a2; h3[e] = f2bf(r2);
  }
  unsigned short* dh = pack + (size_t)m * 786432 + p * 16384 + ko * 256 + r * 8;
  *(ushort8v*)dh = h1;
  *(ushort8v*)(dh + 262144) = h2;
  *(ushort8v*)(dh + 524288) = h3;
}

// ---------------------------------------------------------------------------
// Kernel P: six 512^3 GEMMs C = X*W^T + b via 3-level bf16 split MFMA.
// 6 MFMAs per k-step: h1g1 + h2g1 + h1g2 + h3g1 + h2g2 + h1g3; dropped terms
// are <= 2^-27 relative -> fp32-grade (the 2-way split's 2^-17 failed: dist's
// 1/(a+c)^2 sensitivity amplifies sigma errors where sigmas are tiny).
// Block = 512 threads (8 waves) on a 64x64 tile: waves 0-3 = quadrants for
// K[0,256), waves 4-7 same quadrants for K[256,512); LDS reduce of the halves.
// Fragment loads come straight from the packed layout: coalesced, no LDS.
// C/D layout (verified m74/m101): col = lane&31, row = (i&3)+8*(i>>2)+4*(lane>>5).
// ---------------------------------------------------------------------------
struct GemmArgs { const float* bias[6]; float* out[6]; };

__global__ __launch_bounds__(512) void mfma_proj_kernel(const unsigned short* __restrict__ pack,
                                                        GemmArgs ga) {
  const int p = blockIdx.z;
  const int by = blockIdx.y, bx = blockIdx.x;
  const int t = threadIdx.x, l = t & 63, w = t >> 6;
  const int qd = w & 3, kh = w >> 2;
  const int rowblk = qd >> 1, colblk = qd & 1;
  const int r = l & 31, koff = l >> 5;

  const unsigned short* A = pack + (size_t)p * 786432;
  const unsigned short* B = pack + (size_t)(6 + p) * 786432;
  const int pa = by * 2 + rowblk, pb = bx * 2 + colblk;
  const int ko0 = kh * 32 + koff;
  const size_t aoff = (size_t)pa * 16384 + (size_t)ko0 * 256 + r * 8;
  const size_t boff = (size_t)pb * 16384 + (size_t)ko0 * 256 + r * 8;
  const short8v* A1 = (const short8v*)(A + aoff);
  const short8v* A2 = (const short8v*)(A + 262144 + aoff);
  const short8v* A3 = (const short8v*)(A + 524288 + aoff);
  const short8v* B1 = (const short8v*)(B + boff);
  const short8v* B2 = (const short8v*)(B + 262144 + boff);
  const short8v* B3 = (const short8v*)(B + 524288 + boff);

  f32x16 acc = {};
#pragma unroll 2
  for (int s = 0; s < 16; ++s) {
    short8v a1 = A1[(size_t)s * 64];
    short8v a2 = A2[(size_t)s * 64];
    short8v a3 = A3[(size_t)s * 64];
    short8v b1 = B1[(size_t)s * 64];
    short8v b2 = B2[(size_t)s * 64];
    short8v b3 = B3[(size_t)s * 64];
    acc = __builtin_amdgcn_mfma_f32_32x32x16_bf16(a1, b1, acc, 0, 0, 0);
    acc = __builtin_amdgcn_mfma_f32_32x32x16_bf16(a2, b1, acc, 0, 0, 0);
    acc = __builtin_amdgcn_mfma_f32_32x32x16_bf16(a1, b2, acc, 0, 0, 0);
    acc = __builtin_amdgcn_mfma_f32_32x32x16_bf16(a3, b1, acc, 0, 0, 0);
    acc = __builtin_amdgcn_mfma_f32_32x32x16_bf16(a2, b2, acc, 0, 0, 0);
    acc = __builtin_amdgcn_mfma_f32_32x32x16_bf16(a1, b3, acc, 0, 0, 0);
  }

  __shared__ float red[4][32][33];
  if (kh == 1) {
#pragma unroll
    for (int i = 0; i < 16; ++i) {
      int row = (i & 3) + 8 * (i >> 2) + 4 * (l >> 5);
      red[qd][row][r] = acc[i];
    }
  }
  __syncthreads();
  if (kh == 0) {
    const int colg = bx * 64 + colblk * 32 + r;
    const float bias = ga.bias[p][colg];
    float* C = ga.out[p];
    const int rowbase = by * 64 + rowblk * 32;
#pragma unroll
    for (int i = 0; i < 16; ++i) {
      int row = (i & 3) + 8 * (i >> 2) + 4 * (l >> 5);
      C[(size_t)(rowbase + row) * DM + colg] = acc[i] + red[qd][row][r] + bias;
    }
  }
}

// ---------------------------------------------------------------------------
// Kernel Q: in-place a = sg^2 (+eps), plus per-(s,h) log-sums La/Lc.
// ---------------------------------------------------------------------------
__global__ __launch_bounds__(256) void prep_kernel(float* sq, float* sk, float* sv,
                                                   float* La, float* Lc) {
  const int role = blockIdx.y;
  const int gid  = blockIdx.x * 256 + threadIdx.x;
  const int wid  = gid >> 6;
  const int lane = gid & 63;
  float* buf = (role == 0) ? sq : (role == 1) ? sk : sv;
  const int idx = wid * 64 + lane;
  float v = buf[idx];
  float a = fmaf(v, v, (role == 2) ? 0.f : EPSV);
  buf[idx] = a;
  if (role < 2) {
    float l = __logf(a);
#pragma unroll
    for (int o = 32; o; o >>= 1) l += __shfl_xor(l, o, 64);
    if (lane == 0) ((role == 0) ? La : Lc)[wid] = l;
  }
}

// ---------------------------------------------------------------------------
// Kernel D: distance matrix, lower-triangle 32x32 tiles only.
// ---------------------------------------------------------------------------
__global__ __launch_bounds__(256) void dist_kernel(const float* __restrict__ aq,
                                                   const float* __restrict__ ak,
                                                   const float* __restrict__ mq,
                                                   const float* __restrict__ mk,
                                                   const float* __restrict__ La,
                                                   const float* __restrict__ Lc,
                                                   float* __restrict__ dist) {
  const int blk = blockIdx.x;
  const int h = blk / 136;
  const int tt = blk % 136;
  int qt = (int)((sqrtf(8.f * tt + 1.f) - 1.f) * 0.5f);
  while ((qt + 1) * (qt + 2) / 2 <= tt) ++qt;
  while (qt * (qt + 1) / 2 > tt) --qt;
  const int kt = tt - qt * (qt + 1) / 2;

  __shared__ float aqs[32][68], mqs[32][68], aks[32][68], mks[32][68];
  const int t = threadIdx.x;
#pragma unroll
  for (int i = 0; i < 2; ++i) {
    int idx = t + 256 * i;
    int r = idx >> 4, c4 = idx & 15;
    int gq = (qt * 32 + r) * DM + h * 64 + c4 * 4;
    int gk = (kt * 32 + r) * DM + h * 64 + c4 * 4;
    *(float4*)&aqs[r][c4 * 4] = *(const float4*)&aq[gq];
    *(float4*)&mqs[r][c4 * 4] = *(const float4*)&mq[gq];
    *(float4*)&aks[r][c4 * 4] = *(const float4*)&ak[gk];
    *(float4*)&mks[r][c4 * 4] = *(const float4*)&mk[gk];
  }
  __syncthreads();

  const int qi = t >> 3;
  const int kb = t & 7;
  float accl[4] = {0.f, 0.f, 0.f, 0.f};
  float acct[4] = {0.f, 0.f, 0.f, 0.f};

#pragma unroll 2
  for (int d4 = 0; d4 < 16; ++d4) {
    float4 qa = *(const float4*)&aqs[qi][d4 * 4];
    float4 qm = *(const float4*)&mqs[qi][d4 * 4];
    float qaa[4] = {qa.x, qa.y, qa.z, qa.w};
    float qmm[4] = {qm.x, qm.y, qm.z, qm.w};
#pragma unroll
    for (int j = 0; j < 4; ++j) {
      int ki = kb + 8 * j;
      float4 ca = *(const float4*)&aks[ki][d4 * 4];
      float4 cm = *(const float4*)&mks[ki][d4 * 4];
      float caa[4] = {ca.x, ca.y, ca.z, ca.w};
      float cmm[4] = {cm.x, cm.y, cm.z, cm.w};
#pragma unroll
      for (int e = 0; e < 4; ++e) {
        float s = qaa[e] + caa[e];
        accl[j] += __log2f(s);
        float dm = qmm[e] - cmm[e];
        float rcp = __builtin_amdgcn_rcpf(s - EPSV);
        acct[j] = fmaf(dm * dm, rcp, acct[j]);
      }
    }
  }

  const int qg = qt * 32 + qi;
  const float la = La[qg * 8 + h];
#pragma unroll
  for (int j = 0; j < 4; ++j) {
    int kg = kt * 32 + kb + 8 * j;
    float lc = Lc[kg * 8 + h];
    float dv = (0.5f * LN2F * accl[j] + 0.25f * acct[j]
                - 0.25f * (la + lc) - 32.f * LN2F) * 0.125f;
    dist[(h * SEQ + qg) * SEQ + kg] = dv;
  }
}

// ---------------------------------------------------------------------------
// Kernel S: causal softmax per (h,q) row; zeros k>q so PV reads dense.
// ---------------------------------------------------------------------------
__global__ __launch_bounds__(256) void softmax_kernel(float* __restrict__ dist) {
  const int gid  = blockIdx.x * 256 + threadIdx.x;
  const int wid  = gid >> 6;
  const int lane = gid & 63;
  const int q = wid & 511;
  float* row = dist + wid * SEQ;

  float vals[8];
  float m = -1e30f;
#pragma unroll
  for (int i = 0; i < 8; ++i) {
    int k = lane + 64 * i;
    float v = (k <= q) ? row[k] : -1e30f;
    vals[i] = v;
    m = fmaxf(m, v);
  }
#pragma unroll
  for (int o = 32; o; o >>= 1) m = fmaxf(m, __shfl_xor(m, o, 64));
  float ssum = 0.f;
#pragma unroll
  for (int i = 0; i < 8; ++i) {
    int k = lane + 64 * i;
    float p = (k <= q) ? __expf(vals[i] - m) : 0.f;
    vals[i] = p;
    ssum += p;
  }
#pragma unroll
  for (int o = 32; o; o >>= 1) ssum += __shfl_xor(ssum, o, 64);
  float rs = 1.f / ssum;
#pragma unroll
  for (int i = 0; i < 8; ++i) row[lane + 64 * i] = vals[i] * rs;
}

// ---------------------------------------------------------------------------
// Kernel V: one wave per (h,q) row; lane = d. 4096 waves = 16 waves/CU.
// Causal loop to (q&~7)+8 (attn zeroed beyond q). v/s loads coalesced 256B,
// attn load wave-uniform broadcast. unroll 8 for MLP.
// ---------------------------------------------------------------------------
__global__ __launch_bounds__(256) void pv_kernel(const float* __restrict__ attn,
                                                 const float* __restrict__ mv,
                                                 const float* __restrict__ sv2,
                                                 float* __restrict__ out) {
  const int t   = threadIdx.x;
  const int wid = blockIdx.x * 4 + (t >> 6);   // h*512+q
  const int d   = t & 63;
  const int h = wid >> 9;
  const int q = wid & 511;

  const float* __restrict__ row = attn + (size_t)wid * SEQ;
  const float* __restrict__ vp = mv  + h * 64 + d;
  const float* __restrict__ sp = sv2 + h * 64 + d;

  float am = 0.f, as = 0.f;
  const int kmaxp = (q & ~7) + 8;
#pragma unroll 8
  for (int k = 0; k < kmaxp; ++k) {
    float wgt = row[k];
    float v = vp[(size_t)k * DM];
    float s = sp[(size_t)k * DM];
    am = fmaf(wgt, v, am);
    as = fmaf(wgt, s, as);
  }

  float* out_mu = out;
  float* out_sg = out + NH * SEQ * DKH;
  const int o = wid * DKH + d;
  out_mu[o] = am;
  out_sg[o] = sqrtf(fmaxf(as, 0.f) + EPSV);
}

// ---------------------------------------------------------------------------
extern "C" void kernel_launch(void* const* d_in, const int* in_sizes, int n_in,
                              void* d_out, int out_size, void* d_ws, size_t ws_size,
                              hipStream_t stream) {
  (void)in_sizes; (void)n_in; (void)out_size; (void)ws_size;

  float* ws = (float*)d_ws;
  float* mq = ws;                 // 512*512 each
  float* mk = mq + 262144;
  float* mv = mk + 262144;
  float* sq = mv + 262144;        // becomes aq in-place
  float* sk = sq + 262144;        // becomes ak in-place
  float* sv = sk + 262144;        // becomes sv^2 in-place
  float* La = sv + 262144;        // 4096
  float* Lc = La + 4096;          // 4096
  // pack region: 12 matrices x 3 levels x 512KB = 18 MB. Dead after the GEMM,
  // so dist (8 MB) aliases its start (GEMM -> prep -> dist strictly ordered).
  unsigned short* pack = (unsigned short*)(Lc + 4096);
  float* dist = (float*)pack;

  ConvArgs ca;
  ca.src[0] = (const float*)d_in[0];  // query
  ca.src[1] = (const float*)d_in[1];  // key
  ca.src[2] = (const float*)d_in[2];  // value
  ca.src[3] = (const float*)d_in[3];  // query_sigma
  ca.src[4] = (const float*)d_in[4];  // key_sigma
  ca.src[5] = (const float*)d_in[5];  // value_sigma
  ca.src[6] = (const float*)d_in[6];   // wq_mu
  ca.src[7] = (const float*)d_in[8];   // wk_mu
  ca.src[8] = (const float*)d_in[10];  // wv_mu
  ca.src[9] = (const float*)d_in[12];  // wq_s
  ca.src[10] = (const float*)d_in[14]; // wk_s
  ca.src[11] = (const float*)d_in[16]; // wv_s

  GemmArgs gaArgs;
  gaArgs.bias[0] = (const float*)d_in[7];  gaArgs.out[0] = mq;
  gaArgs.bias[1] = (const float*)d_in[9];  gaArgs.out[1] = mk;
  gaArgs.bias[2] = (const float*)d_in[11]; gaArgs.out[2] = mv;
  gaArgs.bias[3] = (const float*)d_in[13]; gaArgs.out[3] = sq;
  gaArgs.bias[4] = (const float*)d_in[15]; gaArgs.out[4] = sk;
  gaArgs.bias[5] = (const float*)d_in[17]; gaArgs.out[5] = sv;

  convert_kernel<<<12 * 128, 256, 0, stream>>>(ca, pack);

  dim3 ggrid(8, 8, 6);
  mfma_proj_kernel<<<ggrid, 512, 0, stream>>>(pack, gaArgs);

  dim3 qgrid(1024, 3);
  prep_kernel<<<qgrid, 256, 0, stream>>>(sq, sk, sv, La, Lc);

  dist_kernel<<<8 * 136, 256, 0, stream>>>(sq, sk, mq, mk, La, Lc, dist);

  softmax_kernel<<<1024, 256, 0, stream>>>(dist);

  pv_kernel<<<1024, 256, 0, stream>>>(dist, mv, sv, (float*)d_out);
}

// Round 5
// 170.694 us; speedup vs baseline: 1.7894x; 1.1322x over previous
//
#include <hip/hip_runtime.h>
#include <hip/hip_bf16.h>
#include <math.h>

#define SEQ 512
#define DM 512
#define NH 8
#define DKH 64
#define EPSV 1e-6f
#define LN2F 0.6931471805599453f

typedef __attribute__((ext_vector_type(8))) short short8v;
typedef __attribute__((ext_vector_type(8))) unsigned short ushort8v;
typedef __attribute__((ext_vector_type(16))) float f32x16;

__device__ inline unsigned short f2bf(float x) {
  union { float f; unsigned u; } v; v.f = x;
  unsigned r = v.u + 0x7FFFu + ((v.u >> 16) & 1u);
  return (unsigned short)(r >> 16);
}
__device__ inline float bf2f(unsigned short h) {
  union { float f; unsigned u; } v; v.u = ((unsigned)h) << 16;
  return v.f;
}

// ---------------------------------------------------------------------------
// Kernel C: convert 12 fp32 512x512 matrices (6 X, 6 W) into a 3-level bf16
// split (x = h1 + h2 + h3, representation error ~2^-27 |x|) in fragment-ready
// layout: pack[m][level][panel p][k-octet ko][row r][8 bf16].
// ---------------------------------------------------------------------------
struct ConvArgs { const float* src[12]; };

__global__ __launch_bounds__(256) void convert_kernel(ConvArgs a,
                                                      unsigned short* __restrict__ pack) {
  const int m = blockIdx.x >> 7;                        // matrix 0..11
  const int g = ((blockIdx.x & 127) << 8) + threadIdx.x; // 0..32767
  const int r = g & 31, ko = (g >> 5) & 63, p = g >> 11;
  const float* src = a.src[m] + (p * 32 + r) * DM + ko * 8;
  float4 x0 = *(const float4*)src;
  float4 x1 = *(const float4*)(src + 4);
  float xs[8] = {x0.x, x0.y, x0.z, x0.w, x1.x, x1.y, x1.z, x1.w};
  ushort8v h1, h2, h3;
#pragma unroll
  for (int e = 0; e < 8; ++e) {
    unsigned short a1 = f2bf(xs[e]);
    float r1 = xs[e] - bf2f(a1);
    unsigned short a2 = f2bf(r1);
    float r2 = r1 - bf2f(a2);
    h1[e] = a1; h2[e] = a2; h3[e] = f2bf(r2);
  }
  unsigned short* dh = pack + (size_t)m * 786432 + p * 16384 + ko * 256 + r * 8;
  *(ushort8v*)dh = h1;
  *(ushort8v*)(dh + 262144) = h2;
  *(ushort8v*)(dh + 524288) = h3;
}

// ---------------------------------------------------------------------------
// Kernel P: six 512^3 GEMMs C = X*W^T + b via 3-level bf16 split MFMA.
// C/D layout (verified m74/m101): col = lane&31, row = (i&3)+8*(i>>2)+4*(lane>>5).
// ---------------------------------------------------------------------------
struct GemmArgs { const float* bias[6]; float* out[6]; };

__global__ __launch_bounds__(512) void mfma_proj_kernel(const unsigned short* __restrict__ pack,
                                                        GemmArgs ga) {
  const int p = blockIdx.z;
  const int by = blockIdx.y, bx = blockIdx.x;
  const int t = threadIdx.x, l = t & 63, w = t >> 6;
  const int qd = w & 3, kh = w >> 2;
  const int rowblk = qd >> 1, colblk = qd & 1;
  const int r = l & 31, koff = l >> 5;

  const unsigned short* A = pack + (size_t)p * 786432;
  const unsigned short* B = pack + (size_t)(6 + p) * 786432;
  const int pa = by * 2 + rowblk, pb = bx * 2 + colblk;
  const int ko0 = kh * 32 + koff;
  const size_t aoff = (size_t)pa * 16384 + (size_t)ko0 * 256 + r * 8;
  const size_t boff = (size_t)pb * 16384 + (size_t)ko0 * 256 + r * 8;
  const short8v* A1 = (const short8v*)(A + aoff);
  const short8v* A2 = (const short8v*)(A + 262144 + aoff);
  const short8v* A3 = (const short8v*)(A + 524288 + aoff);
  const short8v* B1 = (const short8v*)(B + boff);
  const short8v* B2 = (const short8v*)(B + 262144 + boff);
  const short8v* B3 = (const short8v*)(B + 524288 + boff);

  f32x16 acc = {};
#pragma unroll 2
  for (int s = 0; s < 16; ++s) {
    short8v a1 = A1[(size_t)s * 64];
    short8v a2 = A2[(size_t)s * 64];
    short8v a3 = A3[(size_t)s * 64];
    short8v b1 = B1[(size_t)s * 64];
    short8v b2 = B2[(size_t)s * 64];
    short8v b3 = B3[(size_t)s * 64];
    acc = __builtin_amdgcn_mfma_f32_32x32x16_bf16(a1, b1, acc, 0, 0, 0);
    acc = __builtin_amdgcn_mfma_f32_32x32x16_bf16(a2, b1, acc, 0, 0, 0);
    acc = __builtin_amdgcn_mfma_f32_32x32x16_bf16(a1, b2, acc, 0, 0, 0);
    acc = __builtin_amdgcn_mfma_f32_32x32x16_bf16(a3, b1, acc, 0, 0, 0);
    acc = __builtin_amdgcn_mfma_f32_32x32x16_bf16(a2, b2, acc, 0, 0, 0);
    acc = __builtin_amdgcn_mfma_f32_32x32x16_bf16(a1, b3, acc, 0, 0, 0);
  }

  __shared__ float red[4][32][33];
  if (kh == 1) {
#pragma unroll
    for (int i = 0; i < 16; ++i) {
      int row = (i & 3) + 8 * (i >> 2) + 4 * (l >> 5);
      red[qd][row][r] = acc[i];
    }
  }
  __syncthreads();
  if (kh == 0) {
    const int colg = bx * 64 + colblk * 32 + r;
    const float bias = ga.bias[p][colg];
    float* C = ga.out[p];
    const int rowbase = by * 64 + rowblk * 32;
#pragma unroll
    for (int i = 0; i < 16; ++i) {
      int row = (i & 3) + 8 * (i >> 2) + 4 * (l >> 5);
      C[(size_t)(rowbase + row) * DM + colg] = acc[i] + red[qd][row][r] + bias;
    }
  }
}

// ---------------------------------------------------------------------------
// Kernel Q: in-place a = sg^2 (+eps), plus per-(s,h) log-sums La/Lc.
// ---------------------------------------------------------------------------
__global__ __launch_bounds__(256) void prep_kernel(float* sq, float* sk, float* sv,
                                                   float* La, float* Lc) {
  const int role = blockIdx.y;
  const int gid  = blockIdx.x * 256 + threadIdx.x;
  const int wid  = gid >> 6;
  const int lane = gid & 63;
  float* buf = (role == 0) ? sq : (role == 1) ? sk : sv;
  const int idx = wid * 64 + lane;
  float v = buf[idx];
  float a = fmaf(v, v, (role == 2) ? 0.f : EPSV);
  buf[idx] = a;
  if (role < 2) {
    float l = __logf(a);
#pragma unroll
    for (int o = 32; o; o >>= 1) l += __shfl_xor(l, o, 64);
    if (lane == 0) ((role == 0) ? La : Lc)[wid] = l;
  }
}

// ---------------------------------------------------------------------------
// Kernel D: distance matrix, lower-triangle 32x32 tiles only.
// ---------------------------------------------------------------------------
__global__ __launch_bounds__(256) void dist_kernel(const float* __restrict__ aq,
                                                   const float* __restrict__ ak,
                                                   const float* __restrict__ mq,
                                                   const float* __restrict__ mk,
                                                   const float* __restrict__ La,
                                                   const float* __restrict__ Lc,
                                                   float* __restrict__ dist) {
  const int blk = blockIdx.x;
  const int h = blk / 136;
  const int tt = blk % 136;
  int qt = (int)((sqrtf(8.f * tt + 1.f) - 1.f) * 0.5f);
  while ((qt + 1) * (qt + 2) / 2 <= tt) ++qt;
  while (qt * (qt + 1) / 2 > tt) --qt;
  const int kt = tt - qt * (qt + 1) / 2;

  __shared__ float aqs[32][68], mqs[32][68], aks[32][68], mks[32][68];
  const int t = threadIdx.x;
#pragma unroll
  for (int i = 0; i < 2; ++i) {
    int idx = t + 256 * i;
    int r = idx >> 4, c4 = idx & 15;
    int gq = (qt * 32 + r) * DM + h * 64 + c4 * 4;
    int gk = (kt * 32 + r) * DM + h * 64 + c4 * 4;
    *(float4*)&aqs[r][c4 * 4] = *(const float4*)&aq[gq];
    *(float4*)&mqs[r][c4 * 4] = *(const float4*)&mq[gq];
    *(float4*)&aks[r][c4 * 4] = *(const float4*)&ak[gk];
    *(float4*)&mks[r][c4 * 4] = *(const float4*)&mk[gk];
  }
  __syncthreads();

  const int qi = t >> 3;
  const int kb = t & 7;
  float accl[4] = {0.f, 0.f, 0.f, 0.f};
  float acct[4] = {0.f, 0.f, 0.f, 0.f};

#pragma unroll 2
  for (int d4 = 0; d4 < 16; ++d4) {
    float4 qa = *(const float4*)&aqs[qi][d4 * 4];
    float4 qm = *(const float4*)&mqs[qi][d4 * 4];
    float qaa[4] = {qa.x, qa.y, qa.z, qa.w};
    float qmm[4] = {qm.x, qm.y, qm.z, qm.w};
#pragma unroll
    for (int j = 0; j < 4; ++j) {
      int ki = kb + 8 * j;
      float4 ca = *(const float4*)&aks[ki][d4 * 4];
      float4 cm = *(const float4*)&mks[ki][d4 * 4];
      float caa[4] = {ca.x, ca.y, ca.z, ca.w};
      float cmm[4] = {cm.x, cm.y, cm.z, cm.w};
#pragma unroll
      for (int e = 0; e < 4; ++e) {
        float s = qaa[e] + caa[e];
        accl[j] += __log2f(s);
        float dm = qmm[e] - cmm[e];
        float rcp = __builtin_amdgcn_rcpf(s - EPSV);
        acct[j] = fmaf(dm * dm, rcp, acct[j]);
      }
    }
  }

  const int qg = qt * 32 + qi;
  const float la = La[qg * 8 + h];
#pragma unroll
  for (int j = 0; j < 4; ++j) {
    int kg = kt * 32 + kb + 8 * j;
    float lc = Lc[kg * 8 + h];
    float dv = (0.5f * LN2F * accl[j] + 0.25f * acct[j]
                - 0.25f * (la + lc) - 32.f * LN2F) * 0.125f;
    dist[(h * SEQ + qg) * SEQ + kg] = dv;
  }
}

// ---------------------------------------------------------------------------
// Kernel S: causal softmax; lane owns contiguous k-octet [l*8, l*8+8).
// Writes attn directly as bf16 hi/lo A-fragment packs (same layout as the
// GEMM pack): aPack[h][L][p=q>>5][ko][r=q&31][e]. dist[k>q] is garbage
// (aliased memory) but masked before use.
// ---------------------------------------------------------------------------
__global__ __launch_bounds__(256) void softmax_pack_kernel(const float* __restrict__ dist,
                                                           unsigned short* __restrict__ aPack) {
  const int t = threadIdx.x;
  const int wid = blockIdx.x * 4 + (t >> 6);   // h*512+q
  const int l = t & 63;
  const int h = wid >> 9;
  const int q = wid & 511;
  const float* row = dist + (size_t)wid * SEQ;

  float4 v0 = *(const float4*)&row[l * 8];
  float4 v1 = *(const float4*)&row[l * 8 + 4];
  float vals[8] = {v0.x, v0.y, v0.z, v0.w, v1.x, v1.y, v1.z, v1.w};
  float m = -1e30f;
#pragma unroll
  for (int e = 0; e < 8; ++e) {
    vals[e] = (l * 8 + e <= q) ? vals[e] : -1e30f;
    m = fmaxf(m, vals[e]);
  }
#pragma unroll
  for (int o = 32; o; o >>= 1) m = fmaxf(m, __shfl_xor(m, o, 64));
  float ssum = 0.f;
#pragma unroll
  for (int e = 0; e < 8; ++e) {
    float p = (l * 8 + e <= q) ? __expf(vals[e] - m) : 0.f;
    vals[e] = p;
    ssum += p;
  }
#pragma unroll
  for (int o = 32; o; o >>= 1) ssum += __shfl_xor(ssum, o, 64);
  float rs = 1.f / ssum;

  ushort8v hi, lo;
#pragma unroll
  for (int e = 0; e < 8; ++e) {
    float p = vals[e] * rs;
    unsigned short hh = f2bf(p);
    hi[e] = hh;
    lo[e] = f2bf(p - bf2f(hh));
  }
  unsigned short* dst = aPack + (size_t)h * 524288 + (q >> 5) * 16384 + l * 256 + (q & 31) * 8;
  *(ushort8v*)dst = hi;
  *(ushort8v*)(dst + 262144) = lo;
}

// ---------------------------------------------------------------------------
// Kernel T: pack Vt[d][k] = {mu_v, sv2}[k][h*64+d] as bf16 hi/lo B-fragments.
// vPack[(h,m)][L][pd=d>>5][ko][r=d&31][e]; per (h,m) = 65536 ushorts.
// LDS transpose for coalesced read AND conflict-free column access.
// ---------------------------------------------------------------------------
__global__ __launch_bounds__(256) void pvpack_kernel(const float* __restrict__ mv,
                                                     const float* __restrict__ sv2,
                                                     unsigned short* __restrict__ vPack) {
  const int h = blockIdx.x >> 1;
  const int mm = blockIdx.x & 1;
  const float* src = (mm == 0) ? mv : sv2;
  __shared__ float tile[64][65];
  const int t = threadIdx.x;
  unsigned short* base = vPack + (size_t)(h * 2 + mm) * 65536;

  for (int k0 = 0; k0 < SEQ; k0 += 64) {
    __syncthreads();
#pragma unroll
    for (int i = 0; i < 4; ++i) {
      int idx = t + 256 * i;          // 0..1023
      int r = idx >> 4, c4 = idx & 15;
      float4 v = *(const float4*)&src[(size_t)(k0 + r) * DM + h * 64 + c4 * 4];
      tile[r][c4 * 4 + 0] = v.x; tile[r][c4 * 4 + 1] = v.y;
      tile[r][c4 * 4 + 2] = v.z; tile[r][c4 * 4 + 3] = v.w;
    }
    __syncthreads();
#pragma unroll
    for (int i = 0; i < 2; ++i) {
      int idx = t + 256 * i;          // 0..511
      int d = idx & 63, ko = idx >> 6;
      ushort8v hi, lo;
#pragma unroll
      for (int e = 0; e < 8; ++e) {
        float x = tile[ko * 8 + e][d];
        unsigned short hh = f2bf(x);
        hi[e] = hh;
        lo[e] = f2bf(x - bf2f(hh));
      }
      int koG = (k0 >> 3) + ko;
      unsigned short* dst = base + (d >> 5) * 16384 + koG * 256 + (d & 31) * 8;
      *(ushort8v*)dst = hi;
      *(ushort8v*)(dst + 32768) = lo;
    }
  }
}

// ---------------------------------------------------------------------------
// Kernel V: PV via MFMA. Block = (h, 32-row q-tile); 4 waves:
// wave w -> (d-tile = w&1, matrix = w>>1). Causal k-steps only.
// 3 MFMAs per K=16 step: a_hi*b_hi + a_lo*b_hi + a_hi*b_lo (err ~2^-18).
// ---------------------------------------------------------------------------
__global__ __launch_bounds__(256) void pv_mfma_kernel(const unsigned short* __restrict__ aPack,
                                                      const unsigned short* __restrict__ vPack,
                                                      float* __restrict__ out) {
  const int h = blockIdx.x >> 4;
  const int qt = blockIdx.x & 15;
  const int t = threadIdx.x, l = t & 63, w = t >> 6;
  const int dt = w & 1, mm = w >> 1;

  const unsigned short* aBase = aPack + (size_t)h * 524288 + qt * 16384
                                + (l >> 5) * 256 + (l & 31) * 8;
  const unsigned short* vBase = vPack + (size_t)(h * 2 + mm) * 65536 + dt * 16384
                                + (l >> 5) * 256 + (l & 31) * 8;

  f32x16 acc = {};
  const int nks = 2 * qt + 2;   // K=16 steps covering k <= qt*32+31
  for (int s = 0; s < nks; ++s) {
    short8v a1 = *(const short8v*)(aBase + (size_t)s * 512);
    short8v a2 = *(const short8v*)(aBase + 262144 + (size_t)s * 512);
    short8v b1 = *(const short8v*)(vBase + (size_t)s * 512);
    short8v b2 = *(const short8v*)(vBase + 32768 + (size_t)s * 512);
    acc = __builtin_amdgcn_mfma_f32_32x32x16_bf16(a1, b1, acc, 0, 0, 0);
    acc = __builtin_amdgcn_mfma_f32_32x32x16_bf16(a2, b1, acc, 0, 0, 0);
    acc = __builtin_amdgcn_mfma_f32_32x32x16_bf16(a1, b2, acc, 0, 0, 0);
  }

  float* dst = out + ((mm == 0) ? 0 : (size_t)NH * SEQ * DKH);
  const int col = dt * 32 + (l & 31);
#pragma unroll
  for (int i = 0; i < 16; ++i) {
    int qrow = (i & 3) + 8 * (i >> 2) + 4 * (l >> 5);
    int q = qt * 32 + qrow;
    float v = acc[i];
    if (mm) v = sqrtf(fmaxf(v, 0.f) + EPSV);
    dst[((size_t)h * SEQ + q) * DKH + col] = v;
  }
}

// ---------------------------------------------------------------------------
extern "C" void kernel_launch(void* const* d_in, const int* in_sizes, int n_in,
                              void* d_out, int out_size, void* d_ws, size_t ws_size,
                              hipStream_t stream) {
  (void)in_sizes; (void)n_in; (void)out_size; (void)ws_size;

  float* ws = (float*)d_ws;
  float* mq = ws;                 // 512*512 each
  float* mk = mq + 262144;
  float* mv = mk + 262144;
  float* sq = mv + 262144;        // becomes aq in-place
  float* sk = sq + 262144;        // becomes ak in-place
  float* sv = sk + 262144;        // becomes sv^2 in-place
  float* La = sv + 262144;        // 4096
  float* Lc = La + 4096;          // 4096
  // pack region: 12 x 3 levels x 512KB = 18 MB, dead after the proj GEMM.
  // Reused as: dist (8 MB) + aPack (8 MB) + vPack (2 MB) = 18 MB exactly.
  unsigned short* pack = (unsigned short*)(Lc + 4096);
  float* dist = (float*)pack;                         // [0, 8MB)
  unsigned short* aPack = pack + 4194304;             // [8MB, 16MB)
  unsigned short* vPack = pack + 8388608;             // [16MB, 18MB)

  ConvArgs ca;
  ca.src[0] = (const float*)d_in[0];
  ca.src[1] = (const float*)d_in[1];
  ca.src[2] = (const float*)d_in[2];
  ca.src[3] = (const float*)d_in[3];
  ca.src[4] = (const float*)d_in[4];
  ca.src[5] = (const float*)d_in[5];
  ca.src[6] = (const float*)d_in[6];
  ca.src[7] = (const float*)d_in[8];
  ca.src[8] = (const float*)d_in[10];
  ca.src[9] = (const float*)d_in[12];
  ca.src[10] = (const float*)d_in[14];
  ca.src[11] = (const float*)d_in[16];

  GemmArgs gaArgs;
  gaArgs.bias[0] = (const float*)d_in[7];  gaArgs.out[0] = mq;
  gaArgs.bias[1] = (const float*)d_in[9];  gaArgs.out[1] = mk;
  gaArgs.bias[2] = (const float*)d_in[11]; gaArgs.out[2] = mv;
  gaArgs.bias[3] = (const float*)d_in[13]; gaArgs.out[3] = sq;
  gaArgs.bias[4] = (const float*)d_in[15]; gaArgs.out[4] = sk;
  gaArgs.bias[5] = (const float*)d_in[17]; gaArgs.out[5] = sv;

  convert_kernel<<<12 * 128, 256, 0, stream>>>(ca, pack);

  dim3 ggrid(8, 8, 6);
  mfma_proj_kernel<<<ggrid, 512, 0, stream>>>(pack, gaArgs);

  dim3 qgrid(1024, 3);
  prep_kernel<<<qgrid, 256, 0, stream>>>(sq, sk, sv, La, Lc);

  dist_kernel<<<8 * 136, 256, 0, stream>>>(sq, sk, mq, mk, La, Lc, dist);

  softmax_pack_kernel<<<1024, 256, 0, stream>>>(dist, aPack);

  pvpack_kernel<<<16, 256, 0, stream>>>(mv, sv, vPack);

  pv_mfma_kernel<<<128, 256, 0, stream>>>(aPack, vPack, (float*)d_out);
}